// Round 4
// baseline (488.330 us; speedup 1.0000x reference)
//
#include <hip/hip_runtime.h>
#include <hip/hip_cooperative_groups.h>
#include <stdint.h>

namespace cg = cooperative_groups;

// Problem dims
#define R_ 8
#define B_ 16
#define S_ 512
#define H_ 1024
#define E_ 32
#define P_ 4
#define M_ (B_*S_)          // 8192 rows

// ---------------- prep: masksum + 7-step vec chain (cooperative) ----
// a_{k+1} = W2 a_k, V[k] = W1 a_k, betas[k] = ab . a_k   (s and m chains)
// grid 128 x 256 (512 waves). One grid.sync per chain iteration.
__global__ __launch_bounds__(256) void prep_kernel(
    const float* __restrict__ aw, const float* __restrict__ ab,
    const float* __restrict__ sw, const float* __restrict__ mw,
    const float* __restrict__ tmask,
    float* __restrict__ a_s, float* __restrict__ a_m,
    float* __restrict__ V, float* __restrict__ betas, float* __restrict__ msum)
{
  cg::grid_group grid = cg::this_grid();
  const int nwaves = (int)((gridDim.x * blockDim.x) >> 6);
  const int gwid   = (int)((blockIdx.x * blockDim.x + threadIdx.x) >> 6);
  const int lane   = threadIdx.x & 63;

  // masksum by block 0 (independent of the chain)
  if (blockIdx.x == 0){
    __shared__ float red[4];
    float s = 0.f;
    for (int i = threadIdx.x; i < B_*S_; i += 256) s += tmask[i];
    #pragma unroll
    for (int m = 32; m >= 1; m >>= 1) s += __shfl_xor(s, m, 64);
    if (lane == 0) red[threadIdx.x >> 6] = s;
    __syncthreads();
    if (threadIdx.x == 0) msum[0] = red[0] + red[1] + red[2] + red[3];
  }

  for (int k = 0; k < 7; k++){
    const float* as_k = (k == 0) ? (sw + 2*H_) : (a_s + (size_t)k*H_);
    const float* am_k = (k == 0) ? (mw + 2*H_) : (a_m + (size_t)k*H_);
    for (int w = gwid; w < H_ + 2; w += nwaves){
      if (w < H_){
        const float* w1 = aw + (size_t)w * H_;
        const float* w2 = aw + (size_t)(H_ + w) * H_;
        float vs = 0.f, vm = 0.f, ns = 0.f, nm = 0.f;
        #pragma unroll
        for (int i = 0; i < 4; i++){
          int c = i*256 + lane*4;
          float4 r1 = *(const float4*)(w1 + c);
          float4 r2 = *(const float4*)(w2 + c);
          float4 xs = *(const float4*)(as_k + c);
          float4 xm = *(const float4*)(am_k + c);
          vs += r1.x*xs.x + r1.y*xs.y + r1.z*xs.z + r1.w*xs.w;
          vm += r1.x*xm.x + r1.y*xm.y + r1.z*xm.z + r1.w*xm.w;
          ns += r2.x*xs.x + r2.y*xs.y + r2.z*xs.z + r2.w*xs.w;
          nm += r2.x*xm.x + r2.y*xm.y + r2.z*xm.z + r2.w*xm.w;
        }
        #pragma unroll
        for (int m = 32; m >= 1; m >>= 1){
          vs += __shfl_xor(vs, m, 64); vm += __shfl_xor(vm, m, 64);
          ns += __shfl_xor(ns, m, 64); nm += __shfl_xor(nm, m, 64);
        }
        if (lane == 0){
          V[(size_t)k*H_ + w]       = vs;
          V[(size_t)(7 + k)*H_ + w] = vm;
          a_s[(size_t)(k+1)*H_ + w] = ns;
          a_m[(size_t)(k+1)*H_ + w] = nm;
        }
      } else {
        const float* av = (w == H_) ? as_k : am_k;
        float d = 0.f;
        #pragma unroll
        for (int i = 0; i < 4; i++){
          int c = i*256 + lane*4;
          float4 r1 = *(const float4*)(ab + c);
          float4 xs = *(const float4*)(av + c);
          d += r1.x*xs.x + r1.y*xs.y + r1.z*xs.z + r1.w*xs.w;
        }
        #pragma unroll
        for (int m = 32; m >= 1; m >>= 1) d += __shfl_xor(d, m, 64);
        if (lane == 0) betas[(w == H_ ? 0 : 8) + k] = d;
      }
    }
    __threadfence();
    grid.sync();
  }
}

// ---------------- fused dots: sr_s/sr_m, tok_s + G[14], ent_m ----
__global__ void dots_kernel(const float* __restrict__ sr, const float* __restrict__ tok,
                            const float* __restrict__ ent, const float* __restrict__ sw,
                            const float* __restrict__ mw, const float* __restrict__ V,
                            float* __restrict__ sr_s, float* __restrict__ sr_m,
                            float* __restrict__ tok_s, float* __restrict__ ent_m,
                            float* __restrict__ G){
  int w = (int)((blockIdx.x * blockDim.x + threadIdx.x) >> 6);
  int lane = threadIdx.x & 63;
  if (w < R_*B_*S_){
    const float* rp = sr + (size_t)w * H_;
    float a0 = 0.f, a1 = 0.f;
    #pragma unroll
    for (int i = 0; i < 4; i++){
      int c = i*256 + lane*4;
      float4 v  = *(const float4*)(rp + c);
      float4 ws = *(const float4*)(sw + c);
      float4 wm = *(const float4*)(mw + c);
      a0 += v.x*ws.x + v.y*ws.y + v.z*ws.z + v.w*ws.w;
      a1 += v.x*wm.x + v.y*wm.y + v.z*wm.z + v.w*wm.w;
    }
    #pragma unroll
    for (int m = 32; m >= 1; m >>= 1){ a0 += __shfl_xor(a0, m, 64); a1 += __shfl_xor(a1, m, 64); }
    if (lane == 0){ sr_s[w] = a0; sr_m[w] = a1; }
  } else if (w < R_*B_*S_ + B_*S_){
    int rr = w - R_*B_*S_;
    const float* rp = tok + (size_t)rr * H_;
    float acc[15] = {};
    #pragma unroll
    for (int i = 0; i < 4; i++){
      int c = i*256 + lane*4;
      float4 v  = *(const float4*)(rp + c);
      float4 ws = *(const float4*)(sw + H_ + c);
      acc[0] += v.x*ws.x + v.y*ws.y + v.z*ws.z + v.w*ws.w;
      #pragma unroll
      for (int q = 0; q < 14; q++){
        float4 vv = *(const float4*)(V + (size_t)q*H_ + c);
        acc[q+1] += v.x*vv.x + v.y*vv.y + v.z*vv.z + v.w*vv.w;
      }
    }
    #pragma unroll
    for (int q = 0; q < 15; q++)
      #pragma unroll
      for (int m = 32; m >= 1; m >>= 1) acc[q] += __shfl_xor(acc[q], m, 64);
    if (lane == 0){
      tok_s[rr] = acc[0];
      #pragma unroll
      for (int q = 0; q < 14; q++) G[(size_t)q*M_ + rr] = acc[q+1];
    }
  } else if (w < R_*B_*S_ + 2*B_*S_){
    int rr = w - R_*B_*S_ - B_*S_;
    const float* rp = ent + (size_t)rr * H_;
    float a0 = 0.f;
    #pragma unroll
    for (int i = 0; i < 4; i++){
      int c = i*256 + lane*4;
      float4 v  = *(const float4*)(rp + c);
      float4 wm = *(const float4*)(mw + H_ + c);
      a0 += v.x*wm.x + v.y*wm.y + v.z*wm.z + v.w*wm.w;
    }
    #pragma unroll
    for (int m = 32; m >= 1; m >>= 1) a0 += __shfl_xor(a0, m, 64);
    if (lane == 0) ent_m[rr] = a0;
  }
}

// ---------------- all 8 roles fused (cooperative, 16 blocks x 512) ----
// Block b owns batch row b; thread t owns position t. arg history in regs.
// Per role: stage1 compute own logits -> xb[(r&1)] ; grid.sync ;
//           stage2 batch-softmax (online, reads all 16 rows) + scatter +
//           span-merge + arg + CE loss.
__global__ __launch_bounds__(512) void roles_kernel(
    const float* __restrict__ sr_s, const float* __restrict__ sr_m,
    const float* __restrict__ tok_s, const float* __restrict__ ent_m,
    const float* __restrict__ G, const float* __restrict__ betas,
    const float* __restrict__ sb, const float* __restrict__ mb,
    const int* __restrict__ c2t, const int* __restrict__ e2t,
    const int* __restrict__ spans, const int* __restrict__ labels,
    const float* __restrict__ msum, float* __restrict__ out,
    float* __restrict__ xb)
{
  cg::grid_group grid = cg::this_grid();
  __shared__ float pta[S_];
  __shared__ float merged[S_];
  __shared__ float es[E_];
  __shared__ float red[8];
  __shared__ int   spn[E_*P_*2];
  const int b = blockIdx.x;
  const int t = threadIdx.x;
  const int bs = b*S_ + t;
  const int wid = t >> 6, lane = t & 63;

  if (b == 0 && t == 0) out[0] = 0.f;     // loss accumulator (ordered by sync 0)
  if (t < E_*P_*2) spn[t] = spans[b*(E_*P_*2) + t];
  const int c_own = c2t[bs];
  const int e_own = e2t[bs];
  const float sb0 = sb[0], mb0 = mb[0];
  const float tok_sv = tok_s[bs], ent_mv = ent_m[bs];

  float ah[R_];              // own-row arg history (static-indexed via full unroll)
  float bsum_s = 0.f, bsum_m = 0.f;

  #pragma unroll
  for (int r = 0; r < R_; r++){
    // ---- stage 1: own-row logits ----
    float ps = 0.f, pm = 0.f;
    #pragma unroll
    for (int j = 0; j < R_; j++){
      if (j < r){
        ps += ah[j] * G[(size_t)(r-1-j)*M_ + bs];
        pm += ah[j] * G[(size_t)(7 + r-1-j)*M_ + bs];
      }
    }
    float x = sr_s[(size_t)(r*B_ + b)*S_ + t] + tok_sv + ps + sb0 + bsum_s;
    float y = sr_m[(size_t)(r*B_ + b)*S_ + t] + ent_mv + pm + mb0 + bsum_m;
    float* xc = xb + (size_t)(r & 1) * (2*M_);
    xc[bs] = x;
    xc[M_ + bs] = y;
    __threadfence();
    grid.sync();

    // ---- stage 2: online batch-softmax at position t ----
    float smx = -1e30f, ssum = 0.f, mmx = -1e30f, msv = 0.f;
    #pragma unroll
    for (int bb = 0; bb < B_; bb++){
      float xv = xc[bb*S_ + t];
      float nmx = fmaxf(smx, xv);
      ssum = ssum * __expf(smx - nmx) + __expf(xv - nmx);
      smx = nmx;
      float yv = xc[M_ + bb*S_ + t];
      float nmy = fmaxf(mmx, yv);
      msv = msv * __expf(mmx - nmy) + __expf(yv - nmy);
      mmx = nmy;
    }
    float spv = __expf(x - smx) / ssum;
    float mpv = __expf(y - mmx) / msv;

    // scatter own row (LDS atomics)
    pta[t] = 0.f;
    if (t < E_) es[t] = 0.f;
    __syncthreads();
    if (c_own >= 0) atomicAdd(&pta[c_own], spv);
    if (e_own >= 0) atomicAdd(&es[e_own], mpv);
    __syncthreads();

    // span coverage + max-merge
    float pei = 0.f;
    #pragma unroll
    for (int e = 0; e < E_; e++){
      float sc = es[e];
      #pragma unroll
      for (int p = 0; p < P_; p++){
        int st = spn[e*8 + p*2], en = spn[e*8 + p*2 + 1];
        if (t >= st && t < en) pei += sc;
      }
    }
    float mg = fmaxf(pta[t], pei);
    merged[t] = mg;
    out[1 + (size_t)r*M_ + bs] = mg;
    __syncthreads();

    // own-row arg (kept in register for later roles)
    ah[r] = (c_own >= 0) ? merged[c_own] : 0.f;

    // CE loss for this row
    float mx = mg;
    #pragma unroll
    for (int k = 32; k >= 1; k >>= 1) mx = fmaxf(mx, __shfl_xor(mx, k, 64));
    if (lane == 0) red[wid] = mx;
    __syncthreads();
    float gmx = red[0];
    #pragma unroll
    for (int i = 1; i < 8; i++) gmx = fmaxf(gmx, red[i]);
    float se = __expf(mg - gmx);
    #pragma unroll
    for (int k = 32; k >= 1; k >>= 1) se += __shfl_xor(se, k, 64);
    __syncthreads();
    if (lane == 0) red[wid] = se;
    __syncthreads();
    if (t == 0){
      float tot = 0.f;
      #pragma unroll
      for (int i = 0; i < 8; i++) tot += red[i];
      float lse = gmx + __logf(tot);
      int lbl = labels[r*B_ + b];
      float nll = lse - merged[lbl];
      atomicAdd(out, nll * msum[0] * (1.0f/16.0f));
    }
    __syncthreads();     // protect merged/red before next role reuses LDS

    if (r < 7){ bsum_s += betas[r]; bsum_m += betas[8 + r]; }
  }
}

extern "C" void kernel_launch(void* const* d_in, const int* in_sizes, int n_in,
                              void* d_out, int out_size, void* d_ws, size_t ws_size,
                              hipStream_t stream){
  (void)in_sizes; (void)n_in; (void)out_size; (void)ws_size;
  const int*   labels = (const int*)  d_in[0];
  const float* sr     = (const float*)d_in[1];
  const float* tok    = (const float*)d_in[2];
  const float* ent    = (const float*)d_in[3];
  const float* tmask  = (const float*)d_in[4];
  // d_in[5] entity_mask unused by reference
  const int*   spans  = (const int*)  d_in[6];
  const int*   c2t    = (const int*)  d_in[7];
  const int*   e2t    = (const int*)  d_in[8];
  const float* sw     = (const float*)d_in[9];
  const float* sb     = (const float*)d_in[10];
  const float* mw     = (const float*)d_in[11];
  const float* mb     = (const float*)d_in[12];
  const float* aw     = (const float*)d_in[13];
  const float* ab     = (const float*)d_in[14];
  float* out = (float*)d_out;
  char*  ws  = (char*)d_ws;

  size_t o = 0;
  auto take = [&](size_t bytes){ size_t c = o; o += (bytes + 255) & ~(size_t)255; return c; };
  float* sr_s  = (float*)(ws + take((size_t)R_*B_*S_*4));
  float* sr_m  = (float*)(ws + take((size_t)R_*B_*S_*4));
  float* tok_s = (float*)(ws + take((size_t)B_*S_*4));
  float* ent_m = (float*)(ws + take((size_t)B_*S_*4));
  float* a_s   = (float*)(ws + take((size_t)8*H_*4));
  float* a_m   = (float*)(ws + take((size_t)8*H_*4));
  float* V     = (float*)(ws + take((size_t)14*H_*4));
  float* betas = (float*)(ws + take(64));
  float* G     = (float*)(ws + take((size_t)14*M_*4));
  float* msum  = (float*)(ws + take(256));
  float* xb    = (float*)(ws + take((size_t)2*2*M_*4));

  {
    void* args[] = {(void*)&aw, (void*)&ab, (void*)&sw, (void*)&mw, (void*)&tmask,
                    (void*)&a_s, (void*)&a_m, (void*)&V, (void*)&betas, (void*)&msum};
    hipLaunchCooperativeKernel((void*)prep_kernel, dim3(128), dim3(256), args, 0, stream);
  }
  {
    int waves = R_*B_*S_ + 2*B_*S_;                // 81920
    dots_kernel<<<waves/4, 256, 0, stream>>>(sr, tok, ent, sw, mw, V,
                                             sr_s, sr_m, tok_s, ent_m, G);
  }
  {
    void* args[] = {(void*)&sr_s, (void*)&sr_m, (void*)&tok_s, (void*)&ent_m,
                    (void*)&G, (void*)&betas, (void*)&sb, (void*)&mb,
                    (void*)&c2t, (void*)&e2t, (void*)&spans, (void*)&labels,
                    (void*)&msum, (void*)&out, (void*)&xb};
    hipLaunchCooperativeKernel((void*)roles_kernel, dim3(16), dim3(512), args, 0, stream);
  }
}

// Round 5
// 220.898 us; speedup vs baseline: 2.2107x; 2.2107x over previous
//
#include <hip/hip_runtime.h>
#include <stdint.h>

// Problem dims
#define R_ 8
#define B_ 16
#define S_ 512
#define H_ 1024
#define E_ 32
#define P_ 4
#define M_ (B_*S_)          // 8192 rows

// ---------------- vec chain: a_{k+1} = W2 a_k, V[k] = W1 a_k, beta_k = ab.a_k ----
// aw: answer_w [2H][H] row-major. W1 = rows [0,H), W2 = rows [H,2H).
// V: [14][H]  (q=0..6 -> v^s_k, q=7..13 -> v^m_k); betas: [16] (0..7 s, 8..15 m)
__global__ __launch_bounds__(256) void vec_chain_kernel(
    int k, const float* __restrict__ aw, const float* __restrict__ ab,
    const float* __restrict__ sw, const float* __restrict__ mw,
    float* __restrict__ a_s, float* __restrict__ a_m,
    float* __restrict__ V, float* __restrict__ betas)
{
  int w = (int)((blockIdx.x * blockDim.x + threadIdx.x) >> 6);
  int lane = threadIdx.x & 63;
  const float* as_k = (k == 0) ? (sw + 2*H_) : (a_s + (size_t)k*H_);
  const float* am_k = (k == 0) ? (mw + 2*H_) : (a_m + (size_t)k*H_);
  if (w < H_){
    const float* w1 = aw + (size_t)w * H_;
    const float* w2 = aw + (size_t)(H_ + w) * H_;
    float vs = 0.f, vm = 0.f, ns = 0.f, nm = 0.f;
    #pragma unroll
    for (int i = 0; i < 4; i++){
      int c = i*256 + lane*4;
      float4 r1 = *(const float4*)(w1 + c);
      float4 r2 = *(const float4*)(w2 + c);
      float4 xs = *(const float4*)(as_k + c);
      float4 xm = *(const float4*)(am_k + c);
      vs += r1.x*xs.x + r1.y*xs.y + r1.z*xs.z + r1.w*xs.w;
      vm += r1.x*xm.x + r1.y*xm.y + r1.z*xm.z + r1.w*xm.w;
      ns += r2.x*xs.x + r2.y*xs.y + r2.z*xs.z + r2.w*xs.w;
      nm += r2.x*xm.x + r2.y*xm.y + r2.z*xm.z + r2.w*xm.w;
    }
    #pragma unroll
    for (int m = 32; m >= 1; m >>= 1){
      vs += __shfl_xor(vs, m, 64); vm += __shfl_xor(vm, m, 64);
      ns += __shfl_xor(ns, m, 64); nm += __shfl_xor(nm, m, 64);
    }
    if (lane == 0){
      V[(size_t)k*H_ + w]       = vs;
      V[(size_t)(7 + k)*H_ + w] = vm;
      a_s[(size_t)(k+1)*H_ + w] = ns;
      a_m[(size_t)(k+1)*H_ + w] = nm;
    }
  } else if (w == H_ || w == H_ + 1){
    const float* av = (w == H_) ? as_k : am_k;
    float d = 0.f;
    #pragma unroll
    for (int i = 0; i < 4; i++){
      int c = i*256 + lane*4;
      float4 r1 = *(const float4*)(ab + c);
      float4 xs = *(const float4*)(av + c);
      d += r1.x*xs.x + r1.y*xs.y + r1.z*xs.z + r1.w*xs.w;
    }
    #pragma unroll
    for (int m = 32; m >= 1; m >>= 1) d += __shfl_xor(d, m, 64);
    if (lane == 0) betas[(w == H_ ? 0 : 8) + k] = d;
  }
}

// ---------------- fused dots + init tail ---------------------
// waves [0,65536): sr rows -> sr_s/sr_m
// waves [65536,73728): tok rows -> tok_s + G[14]
// waves [73728,81920): ent rows -> ent_m
// waves [81920,82432): zero PS (512 KB, one float4 per lane)
// wave 82432: masksum + out[0]=0
#define DOTW_ (R_*B_*S_ + 2*B_*S_)     // 81920
__global__ void dots_kernel(const float* __restrict__ sr, const float* __restrict__ tok,
                            const float* __restrict__ ent, const float* __restrict__ sw,
                            const float* __restrict__ mw, const float* __restrict__ V,
                            const float* __restrict__ tmask,
                            float* __restrict__ sr_s, float* __restrict__ sr_m,
                            float* __restrict__ tok_s, float* __restrict__ ent_m,
                            float* __restrict__ G, float* __restrict__ PS,
                            float* __restrict__ msum, float* __restrict__ out){
  int w = (int)((blockIdx.x * blockDim.x + threadIdx.x) >> 6);
  int lane = threadIdx.x & 63;
  if (w < R_*B_*S_){
    const float* rp = sr + (size_t)w * H_;
    float a0 = 0.f, a1 = 0.f;
    #pragma unroll
    for (int i = 0; i < 4; i++){
      int c = i*256 + lane*4;
      float4 v  = *(const float4*)(rp + c);
      float4 ws = *(const float4*)(sw + c);
      float4 wm = *(const float4*)(mw + c);
      a0 += v.x*ws.x + v.y*ws.y + v.z*ws.z + v.w*ws.w;
      a1 += v.x*wm.x + v.y*wm.y + v.z*wm.z + v.w*wm.w;
    }
    #pragma unroll
    for (int m = 32; m >= 1; m >>= 1){ a0 += __shfl_xor(a0, m, 64); a1 += __shfl_xor(a1, m, 64); }
    if (lane == 0){ sr_s[w] = a0; sr_m[w] = a1; }
  } else if (w < R_*B_*S_ + B_*S_){
    int rr = w - R_*B_*S_;
    const float* rp = tok + (size_t)rr * H_;
    float acc[15] = {};
    #pragma unroll
    for (int i = 0; i < 4; i++){
      int c = i*256 + lane*4;
      float4 v  = *(const float4*)(rp + c);
      float4 ws = *(const float4*)(sw + H_ + c);
      acc[0] += v.x*ws.x + v.y*ws.y + v.z*ws.z + v.w*ws.w;
      #pragma unroll
      for (int q = 0; q < 14; q++){
        float4 vv = *(const float4*)(V + (size_t)q*H_ + c);
        acc[q+1] += v.x*vv.x + v.y*vv.y + v.z*vv.z + v.w*vv.w;
      }
    }
    #pragma unroll
    for (int q = 0; q < 15; q++)
      #pragma unroll
      for (int m = 32; m >= 1; m >>= 1) acc[q] += __shfl_xor(acc[q], m, 64);
    if (lane == 0){
      tok_s[rr] = acc[0];
      #pragma unroll
      for (int q = 0; q < 14; q++) G[(size_t)q*M_ + rr] = acc[q+1];
    }
  } else if (w < DOTW_){
    int rr = w - R_*B_*S_ - B_*S_;
    const float* rp = ent + (size_t)rr * H_;
    float a0 = 0.f;
    #pragma unroll
    for (int i = 0; i < 4; i++){
      int c = i*256 + lane*4;
      float4 v  = *(const float4*)(rp + c);
      float4 wm = *(const float4*)(mw + H_ + c);
      a0 += v.x*wm.x + v.y*wm.y + v.z*wm.z + v.w*wm.w;
    }
    #pragma unroll
    for (int m = 32; m >= 1; m >>= 1) a0 += __shfl_xor(a0, m, 64);
    if (lane == 0) ent_m[rr] = a0;
  } else if (w < DOTW_ + 512){
    // zero PS: [8][2][M] floats = 32768 float4s
    int idx = (w - DOTW_)*64 + lane;
    ((float4*)PS)[idx] = make_float4(0.f, 0.f, 0.f, 0.f);
  } else if (w == DOTW_ + 512){
    float s = 0.f;
    for (int i = lane; i < B_*S_; i += 64) s += tmask[i];
    #pragma unroll
    for (int m = 32; m >= 1; m >>= 1) s += __shfl_xor(s, m, 64);
    if (lane == 0){ msum[0] = s; out[0] = 0.f; }
  }
}

// ---------------- per-role kernel with logit handoff ---------
// grid 16 blocks (one per batch row b) x 512 threads (one per s).
// Dispatch r: softmax over batch (logits from xlog, or direct for r=0),
// scatter own row, span-merge, out write, arg, CE loss; then update PS
// prefix sums and write role-(r+1) own-row logits to xlog ping-pong.
__global__ __launch_bounds__(512) void role_kernel(
    int r,
    const float* __restrict__ sr_s, const float* __restrict__ sr_m,
    const float* __restrict__ tok_s, const float* __restrict__ ent_m,
    const float* __restrict__ G, const float* __restrict__ betas,
    const float* __restrict__ sb, const float* __restrict__ mb,
    const int* __restrict__ c2t, const int* __restrict__ e2t,
    const int* __restrict__ spans, const int* __restrict__ labels,
    const float* __restrict__ msum, float* __restrict__ out,
    float* __restrict__ xlog, float* __restrict__ PS)
{
  __shared__ float pta[S_];
  __shared__ float merged[S_];
  __shared__ float es[E_];
  __shared__ float red[8];
  __shared__ int   spn[E_*P_*2];
  const int b = blockIdx.x;
  const int t = threadIdx.x;
  const int bs = b*S_ + t;
  const int wid = t >> 6, lane = t & 63;

  pta[t] = 0.f;
  if (t < E_) es[t] = 0.f;
  if (t < E_*P_*2) spn[t] = spans[b*(E_*P_*2) + t];
  const int c_own = c2t[bs];
  const int e_own = e2t[bs];

  // ---- logits for all batch rows at position t ----
  float sl[B_], ml[B_];
  if (r == 0){
    const float sb0 = sb[0], mb0 = mb[0];
    #pragma unroll
    for (int bb = 0; bb < B_; bb++){
      int q = bb*S_ + t;
      sl[bb] = sr_s[q] + tok_s[q] + sb0;      // (0*B+bb)*S + t == bb*S + t
      ml[bb] = sr_m[q] + ent_m[q] + mb0;
    }
  } else {
    const float* xc = xlog + (size_t)(r & 1) * (2*M_);
    #pragma unroll
    for (int bb = 0; bb < B_; bb++){
      sl[bb] = xc[bb*S_ + t];
      ml[bb] = xc[M_ + bb*S_ + t];
    }
  }
  float smax = -1e30f, mmax = -1e30f;
  #pragma unroll
  for (int bb = 0; bb < B_; bb++){ smax = fmaxf(smax, sl[bb]); mmax = fmaxf(mmax, ml[bb]); }
  float ssum = 0.f, msv = 0.f;
  #pragma unroll
  for (int bb = 0; bb < B_; bb++){ ssum += __expf(sl[bb]-smax); msv += __expf(ml[bb]-mmax); }
  float spv = __expf(sl[b]-smax) / ssum;
  float mpv = __expf(ml[b]-mmax) / msv;

  // ---- scatter own row (LDS atomics) ----
  __syncthreads();
  if (c_own >= 0) atomicAdd(&pta[c_own], spv);
  if (e_own >= 0) atomicAdd(&es[e_own], mpv);
  __syncthreads();

  // ---- span coverage + max-merge ----
  float pei = 0.f;
  #pragma unroll
  for (int e = 0; e < E_; e++){
    float sc = es[e];
    #pragma unroll
    for (int p = 0; p < P_; p++){
      int st = spn[e*8 + p*2], en = spn[e*8 + p*2 + 1];
      if (t >= st && t < en) pei += sc;
    }
  }
  float mg = fmaxf(pta[t], pei);
  merged[t] = mg;
  out[1 + (size_t)r*M_ + bs] = mg;
  __syncthreads();

  // own-row arg for this role
  float ah_r = (c_own >= 0) ? merged[c_own] : 0.f;

  // ---- CE loss for this row ----
  float mx = mg;
  #pragma unroll
  for (int k = 32; k >= 1; k >>= 1) mx = fmaxf(mx, __shfl_xor(mx, k, 64));
  if (lane == 0) red[wid] = mx;
  __syncthreads();
  float gmx = red[0];
  #pragma unroll
  for (int i = 1; i < 8; i++) gmx = fmaxf(gmx, red[i]);
  float se = __expf(mg - gmx);
  #pragma unroll
  for (int k = 32; k >= 1; k >>= 1) se += __shfl_xor(se, k, 64);
  __syncthreads();
  if (lane == 0) red[wid] = se;
  __syncthreads();
  if (t == 0){
    float tot = 0.f;
    #pragma unroll
    for (int i = 0; i < 8; i++) tot += red[i];
    float lse = gmx + __logf(tot);
    int lbl = labels[r*B_ + b];
    float nll = lse - merged[lbl];
    atomicAdd(out, nll * msum[0] * (1.0f/16.0f));
  }

  // ---- prefix-sum update + next-role logit handoff ----
  if (r < 7){
    float ps_next = 0.f, pm_next = 0.f;
    for (int q = r + 1; q <= 7; q++){
      float gs = G[(size_t)(q-1-r)*M_ + bs];
      float gm = G[(size_t)(7 + q-1-r)*M_ + bs];
      float ns = PS[((size_t)q*2 + 0)*M_ + bs] + ah_r * gs;
      float nm = PS[((size_t)q*2 + 1)*M_ + bs] + ah_r * gm;
      PS[((size_t)q*2 + 0)*M_ + bs] = ns;
      PS[((size_t)q*2 + 1)*M_ + bs] = nm;
      if (q == r + 1){ ps_next = ns; pm_next = nm; }
    }
    float bsum_s = 0.f, bsum_m = 0.f;
    for (int k = 0; k <= r; k++){ bsum_s += betas[k]; bsum_m += betas[8 + k]; }
    float xn = sr_s[(size_t)((r+1)*B_ + b)*S_ + t] + tok_s[bs] + ps_next + sb[0] + bsum_s;
    float yn = sr_m[(size_t)((r+1)*B_ + b)*S_ + t] + ent_m[bs] + pm_next + mb[0] + bsum_m;
    float* xn_buf = xlog + (size_t)((r+1) & 1) * (2*M_);
    xn_buf[bs] = xn;
    xn_buf[M_ + bs] = yn;
  }
}

extern "C" void kernel_launch(void* const* d_in, const int* in_sizes, int n_in,
                              void* d_out, int out_size, void* d_ws, size_t ws_size,
                              hipStream_t stream){
  (void)in_sizes; (void)n_in; (void)out_size; (void)ws_size;
  const int*   labels = (const int*)  d_in[0];
  const float* sr     = (const float*)d_in[1];
  const float* tok    = (const float*)d_in[2];
  const float* ent    = (const float*)d_in[3];
  const float* tmask  = (const float*)d_in[4];
  // d_in[5] entity_mask unused by reference
  const int*   spans  = (const int*)  d_in[6];
  const int*   c2t    = (const int*)  d_in[7];
  const int*   e2t    = (const int*)  d_in[8];
  const float* sw     = (const float*)d_in[9];
  const float* sb     = (const float*)d_in[10];
  const float* mw     = (const float*)d_in[11];
  const float* mb     = (const float*)d_in[12];
  const float* aw     = (const float*)d_in[13];
  const float* ab     = (const float*)d_in[14];
  float* out = (float*)d_out;
  char*  ws  = (char*)d_ws;

  size_t o = 0;
  auto take = [&](size_t bytes){ size_t c = o; o += (bytes + 255) & ~(size_t)255; return c; };
  float* sr_s  = (float*)(ws + take((size_t)R_*B_*S_*4));
  float* sr_m  = (float*)(ws + take((size_t)R_*B_*S_*4));
  float* tok_s = (float*)(ws + take((size_t)B_*S_*4));
  float* ent_m = (float*)(ws + take((size_t)B_*S_*4));
  float* a_s   = (float*)(ws + take((size_t)8*H_*4));
  float* a_m   = (float*)(ws + take((size_t)8*H_*4));
  float* V     = (float*)(ws + take((size_t)14*H_*4));
  float* betas = (float*)(ws + take(64));
  float* G     = (float*)(ws + take((size_t)14*M_*4));
  float* PS    = (float*)(ws + take((size_t)8*2*M_*4));   // prefix sums, zeroed in dots
  float* xlog  = (float*)(ws + take((size_t)2*2*M_*4));   // ping-pong logit handoff
  float* msum  = (float*)(ws + take(256));

  for (int k = 0; k < 7; k++)
    vec_chain_kernel<<<257, 256, 0, stream>>>(k, aw, ab, sw, mw, a_s, a_m, V, betas);
  {
    int waves = DOTW_ + 512 + 1;                 // 82433
    int blocks = (waves + 3) / 4;                // 256 thr = 4 waves/block
    dots_kernel<<<blocks, 256, 0, stream>>>(sr, tok, ent, sw, mw, V, tmask,
                                            sr_s, sr_m, tok_s, ent_m, G, PS, msum, out);
  }
  for (int r = 0; r < R_; r++){
    role_kernel<<<16, 512, 0, stream>>>(r, sr_s, sr_m, tok_s, ent_m, G, betas,
                                        sb, mb, c2t, e2t, spans, labels, msum, out,
                                        xlog, PS);
  }
}